// Round 17
// baseline (48.363 us; speedup 1.0000x reference)
//
#include <hip/hip_runtime.h>

typedef __bf16 bf16x8 __attribute__((ext_vector_type(8)));
typedef float f32x4 __attribute__((ext_vector_type(4)));
typedef float f32x16 __attribute__((ext_vector_type(16)));
typedef unsigned short u16;
typedef unsigned int u32;
typedef u32 u32x4 __attribute__((ext_vector_type(4)));
typedef u16 u16x8 __attribute__((ext_vector_type(8)));

#define AS1 __attribute__((address_space(1)))
#define AS3 __attribute__((address_space(3)))
#define GLL16(gp, lp) __builtin_amdgcn_global_load_lds((const AS1 void*)(gp), (AS3 void*)(lp), 16, 0, 0)

__device__ __forceinline__ u16 f32_to_bf16_rne(float f) {
    union { float f; unsigned u; } cv; cv.f = f;
    unsigned u = cv.u;
    return (u16)((u + 0x7FFFu + ((u >> 16) & 1u)) >> 16);
}

__device__ __forceinline__ u32 cvt_pk_bf16(float lo, float hi) {
    u32 r;
    asm("v_cvt_pk_bf16_f32 %0, %1, %2" : "=v"(r) : "v"(lo), "v"(hi));
    return r;
}

// ---- fused prepass: x transpose (bid < 4356) + w4 repack (bid >= 4356) ----
// xT[gslab*2048 + cc*256 + w*8 + j] = bf16(x[b][cc*8+j][d][h][w]), w=0..31
// x32[gslab*64 + cc*8 + j]          = bf16(x[b][cc*8+j][d][h][32])
// w4[(((koff*4+cq)*128 + o)*2 + half)*8 + j] = bf16(w[o*512 + c*8 + koff])
__global__ __launch_bounds__(256) void prepass_kernel(
    const float* __restrict__ x, const float* __restrict__ w,
    u16* __restrict__ xT, u16* __restrict__ x32, u16* __restrict__ w4) {

    const int bid = blockIdx.x;
    const int tid = threadIdx.x;

    if (bid < 4356) {                      // transpose part (proven)
        const int h = bid % 33;
        const int dq = bid / 33;
        const int d = dq % 33;
        const int b = dq / 33;
        const float* xp = x + (size_t)b * 2299968 + d * 1089 + h * 33;

        const int wv  = tid & 31;
        const int cc  = tid >> 5;          // 0..7
        const float* p = xp + (size_t)cc * 8 * 35937 + wv;
        float f0 = p[0],              f1 = p[35937],          f2 = p[2 * 35937], f3 = p[3 * 35937];
        float f4 = p[(size_t)4*35937],f5 = p[(size_t)5*35937],f6 = p[(size_t)6*35937],f7 = p[(size_t)7*35937];
        u32x4 v;
        v[0] = cvt_pk_bf16(f0, f1);
        v[1] = cvt_pk_bf16(f2, f3);
        v[2] = cvt_pk_bf16(f4, f5);
        v[3] = cvt_pk_bf16(f6, f7);
        *reinterpret_cast<u32x4*>(&xT[(size_t)bid * 2048 + cc * 256 + wv * 8]) = v;

        if (tid < 8) {                     // w = 32 column
            const float* q = xp + (size_t)tid * 8 * 35937 + 32;
            u32x4 m;
            m[0] = cvt_pk_bf16(q[0],              q[35937]);
            m[1] = cvt_pk_bf16(q[2 * 35937],      q[3 * 35937]);
            m[2] = cvt_pk_bf16(q[(size_t)4*35937],q[(size_t)5*35937]);
            m[3] = cvt_pk_bf16(q[(size_t)6*35937],q[(size_t)7*35937]);
            *reinterpret_cast<u32x4*>(&x32[(size_t)bid * 64 + tid * 8]) = m;
        }
    } else {                               // w4 repack part (verified R10)
        int e = (bid - 4356) * 256 + tid;  // 65536 total
        int j    = e & 7;
        int half = (e >> 3) & 1;
        int o    = (e >> 4) & 127;
        int cq   = (e >> 11) & 3;
        int koff = (e >> 13) & 7;
        int c = cq * 16 + half * 8 + j;
        w4[e] = f32_to_bf16_rne(w[(o << 9) + (c << 3) + koff]);
    }
}

// ---- old-order repack for the fallback kernel ----
__global__ void repack_w_kernel(const float* __restrict__ w, u16* __restrict__ w3) {
    int e = blockIdx.x * 256 + threadIdx.x;
    int j    = e & 7;
    int g    = (e >> 3) & 3;
    int o    = (e >> 5) & 127;
    int cb   = (e >> 12) & 1;
    int koff = (e >> 13) & 7;
    int c = (cb << 5) + (g << 3) + j;
    w3[e] = f32_to_bf16_rne(w[(o << 9) + (c << 3) + koff]);
}

// ---- conv: ZERO-LDS, ZERO-BARRIER streaming kernel ----
// 1 dz x 4 hy x 128 o per 256t block (4 waves = 4 o-tiles).
// B fragments read DIRECTLY from xT/x32 (xT layout is byte-identical to the
// old LDS slabs): a wave's B-load at (gslab, cc) is a dense 1KB block, same
// pattern as the A-path. The 4 o-tile waves issue identical B addresses
// (L1/L2 broadcast); XCD swizzle keeps the slab set ~2.3MB inside each L2.
// No __shared__, no __syncthreads, no vmcnt drain: every wave self-paced,
// HW scheduler interleaves loads/MFMA/stores across 12 waves/CU.
__global__ __launch_bounds__(256, 3) void conv_mfma_kernel(
    const u16* __restrict__ xT, const u16* __restrict__ x32,
    const u16* __restrict__ w4, float* __restrict__ out) {

    const int tid  = threadIdx.x;
    // XCD swizzle (R13-verified): XCD k owns wgid [128k,128k+128).
    const int bid0 = blockIdx.x;                 // 1024
    const int wgid = ((bid0 & 7) << 7) + (bid0 >> 3);
    const int hyq  = wgid & 7;
    const int plane = wgid >> 3;                 // 128 = 4b * 32dz
    const int dz   = plane & 31;
    const int b    = plane >> 5;
    const int hy0  = hyq << 2;

    const int lane = tid & 63;
    const int l31  = lane & 31;
    const int half = lane >> 5;
    const int o0   = (tid >> 6) << 5;      // wave o-tile base: 0/32/64/96

    const int slab0 = b * 1089 + dz * 33 + hy0;

    f32x16 acc[4];
#pragma unroll
    for (int ht = 0; ht < 4; ++ht)
#pragma unroll
        for (int r = 0; r < 16; ++r)
            acc[ht][r] = 0.f;

    // k = koff*64 + cq*16 + half*8 + j ; koff = kd*4 + kh*2 + kw (R10-13 verified).
    // B(kd, hh) now global: gslab = slab0 + kd*33 + hh. Rolling B over hh = 0..4.
#pragma unroll
    for (int kw = 0; kw < 2; ++kw) {
        const int row = l31 + kw;
#pragma unroll
        for (int cq = 0; cq < 4; ++cq) {
            const int cc = (cq << 1) + half;
            bf16x8 A[2][2];
#pragma unroll
            for (int kd = 0; kd < 2; ++kd)
#pragma unroll
                for (int kh = 0; kh < 2; ++kh) {
                    const int t = (((kd << 2) + (kh << 1) + kw) << 2) + cq;
                    const u16* p = w4 + (t << 11) + ((o0 + l31) << 4) + (half << 3);
                    A[kd][kh] = __builtin_bit_cast(bf16x8, *reinterpret_cast<const u16x8*>(p));
                }
            bf16x8 Bc[2], Bn[2];
#pragma unroll
            for (int kd = 0; kd < 2; ++kd) {
                const int gslab = slab0 + kd * 33;           // hh = 0
                const u16* p = (row < 32)
                    ? xT  + ((size_t)gslab << 11) + (cc << 8) + (row << 3)
                    : x32 + ((size_t)gslab << 6)  + (cc << 3);
                Bc[kd] = __builtin_bit_cast(bf16x8, *reinterpret_cast<const u16x8*>(p));
            }
#pragma unroll
            for (int ht = 0; ht < 4; ++ht) {
#pragma unroll
                for (int kd = 0; kd < 2; ++kd) {
                    const int gslab = slab0 + kd * 33 + ht + 1;
                    const u16* p = (row < 32)
                        ? xT  + ((size_t)gslab << 11) + (cc << 8) + (row << 3)
                        : x32 + ((size_t)gslab << 6)  + (cc << 3);
                    Bn[kd] = __builtin_bit_cast(bf16x8, *reinterpret_cast<const u16x8*>(p));
                }
#pragma unroll
                for (int kd = 0; kd < 2; ++kd) {
                    acc[ht] = __builtin_amdgcn_mfma_f32_32x32x16_bf16(
                        A[kd][0], Bc[kd], acc[ht], 0, 0, 0);
                    acc[ht] = __builtin_amdgcn_mfma_f32_32x32x16_bf16(
                        A[kd][1], Bn[kd], acc[ht], 0, 0, 0);
                }
                Bc[0] = Bn[0];
                Bc[1] = Bn[1];
            }
        }
    }

    // ---- epilogue (R12/R13-verified): per o-row, 4 consecutive hy = 512B ----
    // C/D 32x32: col = lane&31 (w), row = (reg&3)+8*(reg>>2)+4*half (= o)
    float* ob = out + (size_t)b * 128 * 32768 + ((size_t)dz << 10)
                + (hy0 << 5) + l31;
#pragma unroll
    for (int r = 0; r < 16; ++r) {
        const int orow = (r & 3) + ((r >> 2) << 3) + (half << 2);
        float* o2 = ob + ((size_t)(o0 + orow) << 15);
#pragma unroll
        for (int ht = 0; ht < 4; ++ht) {
            float v = acc[ht][r] + 1.0f;
            o2[ht << 5] = v * v;
        }
    }
}

// ================= fallback path (round-4, proven) for small ws =================
#define XS_ROW 72
__global__ __launch_bounds__(256, 4) void conv_mfma_fallback(
    const float* __restrict__ x, const u16* __restrict__ w3, float* __restrict__ out) {

    __shared__ __align__(16) u16 xs[6 * 33 * XS_ROW];

    const int tid = threadIdx.x;
    const int bid = blockIdx.x;
    const int hy0 = (bid & 15) << 1;
    const int dz  = (bid >> 4) & 31;
    const int b   = bid >> 9;

    const float* xb = x + (size_t)b * 64 * 35937;
    for (int i = tid; i < 1584; i += 256) {
        int w   = i % 33;
        int t   = i / 33;
        int q   = t & 7;
        int kh3 = t >> 3;
        int kd  = kh3 >= 3 ? 1 : 0;
        int kh  = kh3 - kd * 3;
        const float* p = xb + (size_t)(q << 3) * 35937 + (dz + kd) * 1089 + (hy0 + kh) * 33 + w;
        u32x4 v;
        v[0] = cvt_pk_bf16(p[0], p[35937]);
        v[1] = cvt_pk_bf16(p[2 * 35937], p[3 * 35937]);
        v[2] = cvt_pk_bf16(p[4 * 35937], p[5 * 35937]);
        v[3] = cvt_pk_bf16(p[6 * 35937], p[7 * 35937]);
        *reinterpret_cast<u32x4*>(&xs[(kh3 * 33 + w) * XS_ROW + (q << 3)]) = v;
    }
    __syncthreads();

    const int lane = tid & 63;
    const int ln   = lane & 15;
    const int g    = lane >> 4;
    const int n0w  = (tid >> 6) << 5;

    f32x4 acc[2][4];
#pragma unroll
    for (int nf = 0; nf < 2; ++nf)
#pragma unroll
        for (int mf = 0; mf < 4; ++mf)
            acc[nf][mf] = (f32x4){0.f, 0.f, 0.f, 0.f};

#pragma unroll
    for (int cb = 0; cb < 2; ++cb) {
        const int cbase = (cb << 5) + (g << 3);
#pragma unroll
        for (int kd = 0; kd < 2; ++kd) {
            bf16x8 wf[2][4];
#pragma unroll
            for (int nf = 0; nf < 2; ++nf)
#pragma unroll
                for (int kk = 0; kk < 4; ++kk) {
                    const int koff = (kd << 2) + kk;
                    const u16* p = w3 + (size_t)((((koff << 1) + cb) << 7)
                                   + n0w + (nf << 4) + ln) * 32 + (g << 3);
                    wf[nf][kk] = __builtin_bit_cast(bf16x8, *reinterpret_cast<const u16x8*>(p));
                }
#pragma unroll
            for (int kw = 0; kw < 2; ++kw) {
                bf16x8 xf[3][2];
#pragma unroll
                for (int hh = 0; hh < 3; ++hh)
#pragma unroll
                    for (int wh = 0; wh < 2; ++wh) {
                        const int rw = (kd * 3 + hh) * 33 + (wh << 4) + ln + kw;
                        xf[hh][wh] = __builtin_bit_cast(bf16x8,
                            *reinterpret_cast<const u16x8*>(&xs[rw * XS_ROW + cbase]));
                    }
#pragma unroll
                for (int kh = 0; kh < 2; ++kh)
#pragma unroll
                    for (int nf = 0; nf < 2; ++nf)
#pragma unroll
                        for (int mf = 0; mf < 4; ++mf)
                            acc[nf][mf] = __builtin_amdgcn_mfma_f32_16x16x32_bf16(
                                wf[nf][(kh << 1) + kw], xf[(mf >> 1) + kh][mf & 1],
                                acc[nf][mf], 0, 0, 0);
            }
        }
    }

    float* ob = out + ((size_t)b * 128) * 32768 + (dz << 10) + (hy0 << 5);
#pragma unroll
    for (int nf = 0; nf < 2; ++nf)
#pragma unroll
        for (int mf = 0; mf < 4; ++mf) {
            const int wx   = ((mf & 1) << 4) + ln;
            const int hrow = mf >> 1;
            float* o2 = ob + (hrow << 5) + wx;
#pragma unroll
            for (int r = 0; r < 4; ++r) {
                const int n = n0w + (nf << 4) + (g << 2) + r;
                float v = acc[nf][mf][r] + 1.0f;
                o2[(size_t)n << 15] = v * v;
            }
        }
}

extern "C" void kernel_launch(void* const* d_in, const int* in_sizes, int n_in,
                              void* d_out, int out_size, void* d_ws, size_t ws_size,
                              hipStream_t stream) {
    const float* x = (const float*)d_in[0];
    const float* w = (const float*)d_in[1];
    float* out = (float*)d_out;

    // ws layout: [w repack: 128KB][xT: 4356*4096 B][x32: 4356*128 B]
    const size_t W_BYTES   = 131072;
    const size_t XT_BYTES  = (size_t)4356 * 4096;
    const size_t X32_BYTES = (size_t)4356 * 128;
    const size_t NEED = W_BYTES + XT_BYTES + X32_BYTES;

    if (ws_size >= NEED) {
        u16* w4  = (u16*)d_ws;
        u16* xT  = (u16*)((char*)d_ws + W_BYTES);
        u16* x32 = (u16*)((char*)d_ws + W_BYTES + XT_BYTES);
        prepass_kernel<<<4612, 256, 0, stream>>>(x, w, xT, x32, w4);
        conv_mfma_kernel<<<1024, 256, 0, stream>>>(xT, x32, w4, out);
    } else {
        u16* w3 = (u16*)d_ws;
        repack_w_kernel<<<256, 256, 0, stream>>>(w, w3);
        conv_mfma_fallback<<<2048, 256, 0, stream>>>(x, w3, out);
    }
}

// Round 18
// 45.712 us; speedup vs baseline: 1.0580x; 1.0580x over previous
//
#include <hip/hip_runtime.h>

typedef __bf16 bf16x8 __attribute__((ext_vector_type(8)));
typedef float f32x4 __attribute__((ext_vector_type(4)));
typedef float f32x16 __attribute__((ext_vector_type(16)));
typedef unsigned short u16;
typedef unsigned int u32;
typedef u32 u32x4 __attribute__((ext_vector_type(4)));
typedef u16 u16x8 __attribute__((ext_vector_type(8)));

#define AS1 __attribute__((address_space(1)))
#define AS3 __attribute__((address_space(3)))
#define GLL16(gp, lp) __builtin_amdgcn_global_load_lds((const AS1 void*)(gp), (AS3 void*)(lp), 16, 0, 0)

__device__ __forceinline__ u16 f32_to_bf16_rne(float f) {
    union { float f; unsigned u; } cv; cv.f = f;
    unsigned u = cv.u;
    return (u16)((u + 0x7FFFu + ((u >> 16) & 1u)) >> 16);
}

__device__ __forceinline__ u32 cvt_pk_bf16(float lo, float hi) {
    u32 r;
    asm("v_cvt_pk_bf16_f32 %0, %1, %2" : "=v"(r) : "v"(lo), "v"(hi));
    return r;
}

// ---- fused prepass: x transpose (bid < 4356) + w4 repack (bid >= 4356) ----
// xT[gslab*2048 + cc*256 + w*8 + j] = bf16(x[b][cc*8+j][d][h][w]), w=0..31
// x32[gslab*64 + cc*8 + j]          = bf16(x[b][cc*8+j][d][h][32])
// w4[(((koff*4+cq)*128 + o)*2 + half)*8 + j] = bf16(w[o*512 + c*8 + koff])
__global__ __launch_bounds__(256) void prepass_kernel(
    const float* __restrict__ x, const float* __restrict__ w,
    u16* __restrict__ xT, u16* __restrict__ x32, u16* __restrict__ w4) {

    const int bid = blockIdx.x;
    const int tid = threadIdx.x;

    if (bid < 4356) {                      // transpose part (proven)
        const int h = bid % 33;
        const int dq = bid / 33;
        const int d = dq % 33;
        const int b = dq / 33;
        const float* xp = x + (size_t)b * 2299968 + d * 1089 + h * 33;

        const int wv  = tid & 31;
        const int cc  = tid >> 5;          // 0..7
        const float* p = xp + (size_t)cc * 8 * 35937 + wv;
        float f0 = p[0],              f1 = p[35937],          f2 = p[2 * 35937], f3 = p[3 * 35937];
        float f4 = p[(size_t)4*35937],f5 = p[(size_t)5*35937],f6 = p[(size_t)6*35937],f7 = p[(size_t)7*35937];
        u32x4 v;
        v[0] = cvt_pk_bf16(f0, f1);
        v[1] = cvt_pk_bf16(f2, f3);
        v[2] = cvt_pk_bf16(f4, f5);
        v[3] = cvt_pk_bf16(f6, f7);
        *reinterpret_cast<u32x4*>(&xT[(size_t)bid * 2048 + cc * 256 + wv * 8]) = v;

        if (tid < 8) {                     // w = 32 column
            const float* q = xp + (size_t)tid * 8 * 35937 + 32;
            u32x4 m;
            m[0] = cvt_pk_bf16(q[0],              q[35937]);
            m[1] = cvt_pk_bf16(q[2 * 35937],      q[3 * 35937]);
            m[2] = cvt_pk_bf16(q[(size_t)4*35937],q[(size_t)5*35937]);
            m[3] = cvt_pk_bf16(q[(size_t)6*35937],q[(size_t)7*35937]);
            *reinterpret_cast<u32x4*>(&x32[(size_t)bid * 64 + tid * 8]) = m;
        }
    } else {                               // w4 repack part (verified R10)
        int e = (bid - 4356) * 256 + tid;  // 65536 total
        int j    = e & 7;
        int half = (e >> 3) & 1;
        int o    = (e >> 4) & 127;
        int cq   = (e >> 11) & 3;
        int koff = (e >> 13) & 7;
        int c = cq * 16 + half * 8 + j;
        w4[e] = f32_to_bf16_rne(w[(o << 9) + (c << 3) + koff]);
    }
}

// ---- old-order repack for the fallback kernel ----
__global__ void repack_w_kernel(const float* __restrict__ w, u16* __restrict__ w3) {
    int e = blockIdx.x * 256 + threadIdx.x;
    int j    = e & 7;
    int g    = (e >> 3) & 3;
    int o    = (e >> 5) & 127;
    int cb   = (e >> 12) & 1;
    int koff = (e >> 13) & 7;
    int c = (cb << 5) + (g << 3) + j;
    w3[e] = f32_to_bf16_rne(w[(o << 9) + (c << 3) + koff]);
}

// ---- staged-tile geometry (R15-verified): 6 slabs (kd 0..1 x hh 0..2) of
// 4096B, sid = kd*3+hh, u16 idx sid*2048 + cc*256 + row*8;
// mini (w=32) at u16 12288 + sid*64 + cc*8.  Buffer = 12672 u16 = 25344 B.
// Stage = EXACTLY 7 vmem instructions per wave (6 main + 1 mini, all waves).
__device__ __forceinline__ void stage_tile(
    const u16* __restrict__ xT, const u16* __restrict__ x32,
    u16* __restrict__ buf, int slab0, int tid) {

    char* ldsb = (char*)buf;
#pragma unroll
    for (int r = 0; r < 6; ++r) {
        const int u  = tid + (r << 8);
        const int kd = r >= 3;
        const int hh = r - kd * 3;
        const char* src = (const char*)xT + ((size_t)(slab0 + kd * 33 + hh) << 12)
                          + ((u & 255) << 4);
        GLL16(src, ldsb + (u << 4));
    }
    // mini: 48 x 16B; lanes<48 of EVERY wave load it (redundant same-data
    // writes are benign) so the per-wave vmem count is uniform (=7).
    const int l = tid & 63;
    if (l < 48) {
        const int sid = l >> 3;
        const int kd  = sid >= 3;
        const int hh  = sid - kd * 3;
        const char* src = (const char*)x32
            + ((size_t)(slab0 + kd * 33 + hh) << 7) + ((l & 7) << 4);
        GLL16(src, ldsb + 24576 + (l << 4));
    }
}

// ---- compute+store one tile from a staged buffer (R15-verified math) ----
__device__ __forceinline__ void process_tile(
    const u16* __restrict__ buf, const u16* __restrict__ w4,
    float* __restrict__ out, int b, int dz, int hy0, int tid) {

    const int lane = tid & 63;
    const int l31  = lane & 31;
    const int half = lane >> 5;
    const int o0   = (tid >> 6) << 5;      // wave o-tile base: 0/32/64/96

    f32x16 acc[2];
#pragma unroll
    for (int ht = 0; ht < 2; ++ht)
#pragma unroll
        for (int r = 0; r < 16; ++r)
            acc[ht][r] = 0.f;

    // k = koff*64 + cq*16 + half*8 + j ; koff = kd*4 + kh*2 + kw.
#pragma unroll
    for (int kw = 0; kw < 2; ++kw) {
        const int row = l31 + kw;
#pragma unroll
        for (int cq = 0; cq < 4; ++cq) {
            const int cc = (cq << 1) + half;
            bf16x8 A[2][2];
#pragma unroll
            for (int kd = 0; kd < 2; ++kd)
#pragma unroll
                for (int kh = 0; kh < 2; ++kh) {
                    const int t = (((kd << 2) + (kh << 1) + kw) << 2) + cq;
                    const u16* p = w4 + (t << 11) + ((o0 + l31) << 4) + (half << 3);
                    A[kd][kh] = __builtin_bit_cast(bf16x8, *reinterpret_cast<const u16x8*>(p));
                }
            bf16x8 Bc[2], Bn[2];
#pragma unroll
            for (int kd = 0; kd < 2; ++kd) {
                const int sid = kd * 3;
                const u16* p = (row < 32)
                    ? &buf[(sid << 11) + (cc << 8) + (row << 3)]
                    : &buf[12288 + (sid << 6) + (cc << 3)];
                Bc[kd] = __builtin_bit_cast(bf16x8, *reinterpret_cast<const u16x8*>(p));
            }
#pragma unroll
            for (int ht = 0; ht < 2; ++ht) {
#pragma unroll
                for (int kd = 0; kd < 2; ++kd) {
                    const int sid = kd * 3 + ht + 1;
                    const u16* p = (row < 32)
                        ? &buf[(sid << 11) + (cc << 8) + (row << 3)]
                        : &buf[12288 + (sid << 6) + (cc << 3)];
                    Bn[kd] = __builtin_bit_cast(bf16x8, *reinterpret_cast<const u16x8*>(p));
                }
#pragma unroll
                for (int kd = 0; kd < 2; ++kd) {
                    acc[ht] = __builtin_amdgcn_mfma_f32_32x32x16_bf16(
                        A[kd][0], Bc[kd], acc[ht], 0, 0, 0);
                    acc[ht] = __builtin_amdgcn_mfma_f32_32x32x16_bf16(
                        A[kd][1], Bn[kd], acc[ht], 0, 0, 0);
                }
                Bc[0] = Bn[0];
                Bc[1] = Bn[1];
            }
        }
    }

    // epilogue (R12-verified): 32 store instrs/thread
    float* ob = out + (size_t)b * 128 * 32768 + ((size_t)dz << 10)
                + (hy0 << 5) + l31;
#pragma unroll
    for (int r = 0; r < 16; ++r) {
        const int orow = (r & 3) + ((r >> 2) << 3) + (half << 2);
        float* o2 = ob + ((size_t)(o0 + orow) << 15);
#pragma unroll
        for (int ht = 0; ht < 2; ++ht) {
            float v = acc[ht][r] + 1.0f;
            o2[ht << 5] = v * v;
        }
    }
}

// ---- conv: persistent 4-tile loop, double-buffered, COUNTED vmcnt (T3+T4) ----
// Block = 256t, 4 consecutive hy-tiles of one (b,dz). 2 LDS buffers (50.7KB),
// grid 512 = 2 blocks/CU. Raw s_barrier only — NO __syncthreads (its implicit
// vmcnt(0) would drain the pipeline). Wait arithmetic (per wave, in-order):
// stage=7 loads, stores=32. Steady state at wait of iter t: queue =
// [stage(t)(7) | stores(t-1)(32) | stage(t+1)(7)] -> vmcnt(39) retires
// stage(t), leaves 39 in flight. t=0: vmcnt(7). t=3 (no stage): vmcnt(32).
__global__ __launch_bounds__(256, 4) void conv_mfma_kernel(
    const u16* __restrict__ xT, const u16* __restrict__ x32,
    const u16* __restrict__ w4, float* __restrict__ out) {

    __shared__ __align__(16) u16 xs[2][12672];   // 50688 B

    const int tid  = threadIdx.x;
    // XCD swizzle: XCD k owns wgid [64k,64k+64) = 16 contiguous (b,dz) planes.
    const int bid0 = blockIdx.x;                 // 512
    const int wgid = ((bid0 & 7) << 6) + (bid0 >> 3);
    const int hq   = wgid & 3;                   // tile group: hyp = hq*4+t
    const int plane = wgid >> 2;                 // 128 = 4b * 32dz
    const int dz   = plane & 31;
    const int b    = plane >> 5;
    const int slabbase = b * 1089 + dz * 33;
    const int hybase   = hq << 3;                // hy0(t) = hybase + 2t

    stage_tile(xT, x32, xs[0], slabbase + hybase, tid);

#pragma unroll
    for (int t = 0; t < 4; ++t) {
        if (t < 3)
            stage_tile(xT, x32, xs[(t + 1) & 1], slabbase + hybase + ((t + 1) << 1), tid);

        if (t == 0)      asm volatile("s_waitcnt vmcnt(7)"  ::: "memory");
        else if (t == 3) asm volatile("s_waitcnt vmcnt(32)" ::: "memory");
        else             asm volatile("s_waitcnt vmcnt(39)" ::: "memory");
        __builtin_amdgcn_sched_barrier(0);
        __builtin_amdgcn_s_barrier();            // all waves' stage(t) landed

        process_tile(xs[t & 1], w4, out, b, dz, hybase + (t << 1), tid);

        __builtin_amdgcn_s_barrier();            // all waves done reading buf
    }
}

// ================= fallback path (round-4, proven) for small ws =================
#define XS_ROW 72
__global__ __launch_bounds__(256, 4) void conv_mfma_fallback(
    const float* __restrict__ x, const u16* __restrict__ w3, float* __restrict__ out) {

    __shared__ __align__(16) u16 xs[6 * 33 * XS_ROW];

    const int tid = threadIdx.x;
    const int bid = blockIdx.x;
    const int hy0 = (bid & 15) << 1;
    const int dz  = (bid >> 4) & 31;
    const int b   = bid >> 9;

    const float* xb = x + (size_t)b * 64 * 35937;
    for (int i = tid; i < 1584; i += 256) {
        int w   = i % 33;
        int t   = i / 33;
        int q   = t & 7;
        int kh3 = t >> 3;
        int kd  = kh3 >= 3 ? 1 : 0;
        int kh  = kh3 - kd * 3;
        const float* p = xb + (size_t)(q << 3) * 35937 + (dz + kd) * 1089 + (hy0 + kh) * 33 + w;
        u32x4 v;
        v[0] = cvt_pk_bf16(p[0], p[35937]);
        v[1] = cvt_pk_bf16(p[2 * 35937], p[3 * 35937]);
        v[2] = cvt_pk_bf16(p[4 * 35937], p[5 * 35937]);
        v[3] = cvt_pk_bf16(p[6 * 35937], p[7 * 35937]);
        *reinterpret_cast<u32x4*>(&xs[(kh3 * 33 + w) * XS_ROW + (q << 3)]) = v;
    }
    __syncthreads();

    const int lane = tid & 63;
    const int ln   = lane & 15;
    const int g    = lane >> 4;
    const int n0w  = (tid >> 6) << 5;

    f32x4 acc[2][4];
#pragma unroll
    for (int nf = 0; nf < 2; ++nf)
#pragma unroll
        for (int mf = 0; mf < 4; ++mf)
            acc[nf][mf] = (f32x4){0.f, 0.f, 0.f, 0.f};

#pragma unroll
    for (int cb = 0; cb < 2; ++cb) {
        const int cbase = (cb << 5) + (g << 3);
#pragma unroll
        for (int kd = 0; kd < 2; ++kd) {
            bf16x8 wf[2][4];
#pragma unroll
            for (int nf = 0; nf < 2; ++nf)
#pragma unroll
                for (int kk = 0; kk < 4; ++kk) {
                    const int koff = (kd << 2) + kk;
                    const u16* p = w3 + (size_t)((((koff << 1) + cb) << 7)
                                   + n0w + (nf << 4) + ln) * 32 + (g << 3);
                    wf[nf][kk] = __builtin_bit_cast(bf16x8, *reinterpret_cast<const u16x8*>(p));
                }
#pragma unroll
            for (int kw = 0; kw < 2; ++kw) {
                bf16x8 xf[3][2];
#pragma unroll
                for (int hh = 0; hh < 3; ++hh)
#pragma unroll
                    for (int wh = 0; wh < 2; ++wh) {
                        const int rw = (kd * 3 + hh) * 33 + (wh << 4) + ln + kw;
                        xf[hh][wh] = __builtin_bit_cast(bf16x8,
                            *reinterpret_cast<const u16x8*>(&xs[rw * XS_ROW + cbase]));
                    }
#pragma unroll
                for (int kh = 0; kh < 2; ++kh)
#pragma unroll
                    for (int nf = 0; nf < 2; ++nf)
#pragma unroll
                        for (int mf = 0; mf < 4; ++mf)
                            acc[nf][mf] = __builtin_amdgcn_mfma_f32_16x16x32_bf16(
                                wf[nf][(kh << 1) + kw], xf[(mf >> 1) + kh][mf & 1],
                                acc[nf][mf], 0, 0, 0);
            }
        }
    }

    float* ob = out + ((size_t)b * 128) * 32768 + (dz << 10) + (hy0 << 5);
#pragma unroll
    for (int nf = 0; nf < 2; ++nf)
#pragma unroll
        for (int mf = 0; mf < 4; ++mf) {
            const int wx   = ((mf & 1) << 4) + ln;
            const int hrow = mf >> 1;
            float* o2 = ob + (hrow << 5) + wx;
#pragma unroll
            for (int r = 0; r < 4; ++r) {
                const int n = n0w + (nf << 4) + (g << 2) + r;
                float v = acc[nf][mf][r] + 1.0f;
                o2[(size_t)n << 15] = v * v;
            }
        }
}

extern "C" void kernel_launch(void* const* d_in, const int* in_sizes, int n_in,
                              void* d_out, int out_size, void* d_ws, size_t ws_size,
                              hipStream_t stream) {
    const float* x = (const float*)d_in[0];
    const float* w = (const float*)d_in[1];
    float* out = (float*)d_out;

    // ws layout: [w repack: 128KB][xT: 4356*4096 B][x32: 4356*128 B]
    const size_t W_BYTES   = 131072;
    const size_t XT_BYTES  = (size_t)4356 * 4096;
    const size_t X32_BYTES = (size_t)4356 * 128;
    const size_t NEED = W_BYTES + XT_BYTES + X32_BYTES;

    if (ws_size >= NEED) {
        u16* w4  = (u16*)d_ws;
        u16* xT  = (u16*)((char*)d_ws + W_BYTES);
        u16* x32 = (u16*)((char*)d_ws + W_BYTES + XT_BYTES);
        prepass_kernel<<<4612, 256, 0, stream>>>(x, w, xT, x32, w4);
        conv_mfma_kernel<<<512, 256, 0, stream>>>(xT, x32, w4, out);
    } else {
        u16* w3 = (u16*)d_ws;
        repack_w_kernel<<<256, 256, 0, stream>>>(w, w3);
        conv_mfma_fallback<<<2048, 256, 0, stream>>>(x, w3, out);
    }
}

// Round 19
// 41.939 us; speedup vs baseline: 1.1532x; 1.0900x over previous
//
#include <hip/hip_runtime.h>

typedef __bf16 bf16x8 __attribute__((ext_vector_type(8)));
typedef float f32x4 __attribute__((ext_vector_type(4)));
typedef float f32x16 __attribute__((ext_vector_type(16)));
typedef unsigned short u16;
typedef unsigned int u32;
typedef u32 u32x4 __attribute__((ext_vector_type(4)));
typedef u16 u16x8 __attribute__((ext_vector_type(8)));

#define AS1 __attribute__((address_space(1)))
#define AS3 __attribute__((address_space(3)))
#define GLL16(gp, lp) __builtin_amdgcn_global_load_lds((const AS1 void*)(gp), (AS3 void*)(lp), 16, 0, 0)

__device__ __forceinline__ u16 f32_to_bf16_rne(float f) {
    union { float f; unsigned u; } cv; cv.f = f;
    unsigned u = cv.u;
    return (u16)((u + 0x7FFFu + ((u >> 16) & 1u)) >> 16);
}

__device__ __forceinline__ u32 cvt_pk_bf16(float lo, float hi) {
    u32 r;
    asm("v_cvt_pk_bf16_f32 %0, %1, %2" : "=v"(r) : "v"(lo), "v"(hi));
    return r;
}

// ---- fused prepass: x transpose (bid < 4356) + w4 repack (bid >= 4356) ----
// xT[gslab*2048 + cc*256 + w*8 + j] = bf16(x[b][cc*8+j][d][h][w]), w=0..31
// x32[gslab*64 + cc*8 + j]          = bf16(x[b][cc*8+j][d][h][32])
// w4[(((koff*4+cq)*128 + o)*2 + half)*8 + j] = bf16(w[o*512 + c*8 + koff])
__global__ __launch_bounds__(256) void prepass_kernel(
    const float* __restrict__ x, const float* __restrict__ w,
    u16* __restrict__ xT, u16* __restrict__ x32, u16* __restrict__ w4) {

    const int bid = blockIdx.x;
    const int tid = threadIdx.x;

    if (bid < 4356) {                      // transpose part (proven)
        const int h = bid % 33;
        const int dq = bid / 33;
        const int d = dq % 33;
        const int b = dq / 33;
        const float* xp = x + (size_t)b * 2299968 + d * 1089 + h * 33;

        const int wv  = tid & 31;
        const int cc  = tid >> 5;          // 0..7
        const float* p = xp + (size_t)cc * 8 * 35937 + wv;
        float f0 = p[0],              f1 = p[35937],          f2 = p[2 * 35937], f3 = p[3 * 35937];
        float f4 = p[(size_t)4*35937],f5 = p[(size_t)5*35937],f6 = p[(size_t)6*35937],f7 = p[(size_t)7*35937];
        u32x4 v;
        v[0] = cvt_pk_bf16(f0, f1);
        v[1] = cvt_pk_bf16(f2, f3);
        v[2] = cvt_pk_bf16(f4, f5);
        v[3] = cvt_pk_bf16(f6, f7);
        *reinterpret_cast<u32x4*>(&xT[(size_t)bid * 2048 + cc * 256 + wv * 8]) = v;

        if (tid < 8) {                     // w = 32 column
            const float* q = xp + (size_t)tid * 8 * 35937 + 32;
            u32x4 m;
            m[0] = cvt_pk_bf16(q[0],              q[35937]);
            m[1] = cvt_pk_bf16(q[2 * 35937],      q[3 * 35937]);
            m[2] = cvt_pk_bf16(q[(size_t)4*35937],q[(size_t)5*35937]);
            m[3] = cvt_pk_bf16(q[(size_t)6*35937],q[(size_t)7*35937]);
            *reinterpret_cast<u32x4*>(&x32[(size_t)bid * 64 + tid * 8]) = m;
        }
    } else {                               // w4 repack part (verified R10)
        int e = (bid - 4356) * 256 + tid;  // 65536 total
        int j    = e & 7;
        int half = (e >> 3) & 1;
        int o    = (e >> 4) & 127;
        int cq   = (e >> 11) & 3;
        int koff = (e >> 13) & 7;
        int c = cq * 16 + half * 8 + j;
        w4[e] = f32_to_bf16_rne(w[(o << 9) + (c << 3) + koff]);
    }
}

// ---- old-order repack for the fallback kernel ----
__global__ void repack_w_kernel(const float* __restrict__ w, u16* __restrict__ w3) {
    int e = blockIdx.x * 256 + threadIdx.x;
    int j    = e & 7;
    int g    = (e >> 3) & 3;
    int o    = (e >> 5) & 127;
    int cb   = (e >> 12) & 1;
    int koff = (e >> 13) & 7;
    int c = (cb << 5) + (g << 3) + j;
    w3[e] = f32_to_bf16_rne(w[(o << 9) + (c << 3) + koff]);
}

// ---- conv: R13 (best, verified) + NON-TEMPORAL epilogue stores ----
// 1 dz x 4 hy x 128 o per 256t block (4 waves = 4 o-tiles).
// LDS: 10 slabs (kd 0..1 x hh 0..4) of 4096B, sid = kd*5+hh,
//      u16 idx sid*2048 + cc*256 + row*8;
//      mini (w=32) at u16 20480 + sid*64 + cc*8.  Total 42240 B.
// Theory: 67MB of temporal stores thrash the 4MB/XCD L2 (write-allocate
// evicts the 2.3MB slab read set + w4 -> refetch, FETCH 20.7MB > 17.8MB).
// 'nt' stores bypass L2 allocation; read set stays resident.
__global__ __launch_bounds__(256, 4) void conv_mfma_kernel(
    const u16* __restrict__ xT, const u16* __restrict__ x32,
    const u16* __restrict__ w4, float* __restrict__ out) {

    __shared__ __align__(16) u16 xs[21120];

    const int tid  = threadIdx.x;
    // XCD swizzle (R13-verified): XCD k owns wgid [128k,128k+128).
    const int bid0 = blockIdx.x;                 // 2048
    const int wgid = ((bid0 & 7) << 8) + (bid0 >> 3);
    const int hyp  = wgid & 15;
    const int plane = wgid >> 4;                 // 128 = 4b * 32dz
    const int dz   = plane & 31;
    const int b    = plane >> 5;
    const int hy0  = hyp << 1;

    // NOTE: R13 used grid 1024 with hyq<<2 (4 hy); keep EXACT R13 geometry:
    // (grid 1024, 4 hy per block). Recompute indices accordingly below.
    (void)hyp; (void)hy0;

    const int wg   = ((bid0 & 7) << 7) + (bid0 >> 3);   // grid 1024 mapping
    const int hyq  = wg & 7;
    const int pl   = wg >> 3;
    const int dz2  = pl & 31;
    const int b2   = pl >> 5;
    const int hyb  = hyq << 2;

    // ---- stage 10 slabs: 2560 x 16B units, 256 threads, 10 exact rounds ----
    char* ldsb = (char*)xs;
    const int slab0 = b2 * 1089 + dz2 * 33 + hyb;
#pragma unroll
    for (int r = 0; r < 10; ++r) {
        const int u   = tid + (r << 8);
        const int kd  = r >= 5;
        const int hh  = r - kd * 5;
        const char* src = (const char*)xT + ((size_t)(slab0 + kd * 33 + hh) << 12)
                          + ((u & 255) << 4);
        GLL16(src, ldsb + (u << 4));
    }
    if (tid < 80) {
        const int sid = tid >> 3;
        const int kd  = sid >= 5;
        const int hh  = sid - kd * 5;
        const char* src = (const char*)x32
            + ((size_t)(slab0 + kd * 33 + hh) << 7) + ((tid & 7) << 4);
        GLL16(src, ldsb + 40960 + (tid << 4));
    }
    asm volatile("s_waitcnt vmcnt(0)" ::: "memory");
    __syncthreads();

    const int lane = tid & 63;
    const int l31  = lane & 31;
    const int half = lane >> 5;
    const int o0   = (tid >> 6) << 5;      // wave o-tile base: 0/32/64/96

    f32x16 acc[4];
#pragma unroll
    for (int ht = 0; ht < 4; ++ht)
#pragma unroll
        for (int r = 0; r < 16; ++r)
            acc[ht][r] = 0.f;

    // k = koff*64 + cq*16 + half*8 + j ; koff = kd*4 + kh*2 + kw (R10-13 verified).
#pragma unroll
    for (int kw = 0; kw < 2; ++kw) {
        const int row = l31 + kw;
#pragma unroll
        for (int cq = 0; cq < 4; ++cq) {
            const int cc = (cq << 1) + half;
            bf16x8 A[2][2];
#pragma unroll
            for (int kd = 0; kd < 2; ++kd)
#pragma unroll
                for (int kh = 0; kh < 2; ++kh) {
                    const int t = (((kd << 2) + (kh << 1) + kw) << 2) + cq;
                    const u16* p = w4 + (t << 11) + ((o0 + l31) << 4) + (half << 3);
                    A[kd][kh] = __builtin_bit_cast(bf16x8, *reinterpret_cast<const u16x8*>(p));
                }
            bf16x8 Bc[2], Bn[2];
#pragma unroll
            for (int kd = 0; kd < 2; ++kd) {
                const int sid = kd * 5;
                const u16* p = (row < 32)
                    ? &xs[(sid << 11) + (cc << 8) + (row << 3)]
                    : &xs[20480 + (sid << 6) + (cc << 3)];
                Bc[kd] = __builtin_bit_cast(bf16x8, *reinterpret_cast<const u16x8*>(p));
            }
#pragma unroll
            for (int ht = 0; ht < 4; ++ht) {
#pragma unroll
                for (int kd = 0; kd < 2; ++kd) {
                    const int sid = kd * 5 + ht + 1;
                    const u16* p = (row < 32)
                        ? &xs[(sid << 11) + (cc << 8) + (row << 3)]
                        : &xs[20480 + (sid << 6) + (cc << 3)];
                    Bn[kd] = __builtin_bit_cast(bf16x8, *reinterpret_cast<const u16x8*>(p));
                }
#pragma unroll
                for (int kd = 0; kd < 2; ++kd) {
                    acc[ht] = __builtin_amdgcn_mfma_f32_32x32x16_bf16(
                        A[kd][0], Bc[kd], acc[ht], 0, 0, 0);
                    acc[ht] = __builtin_amdgcn_mfma_f32_32x32x16_bf16(
                        A[kd][1], Bn[kd], acc[ht], 0, 0, 0);
                }
                Bc[0] = Bn[0];
                Bc[1] = Bn[1];
            }
        }
    }

    // ---- epilogue (R12-verified mapping) with NON-TEMPORAL stores ----
    // C/D 32x32: col = lane&31 (w), row = (reg&3)+8*(reg>>2)+4*half (= o)
    float* ob = out + (size_t)b2 * 128 * 32768 + ((size_t)dz2 << 10)
                + (hyb << 5) + l31;
#pragma unroll
    for (int r = 0; r < 16; ++r) {
        const int orow = (r & 3) + ((r >> 2) << 3) + (half << 2);
        float* o2 = ob + ((size_t)(o0 + orow) << 15);
#pragma unroll
        for (int ht = 0; ht < 4; ++ht) {
            float v = acc[ht][r] + 1.0f;
            __builtin_nontemporal_store(v * v, o2 + (ht << 5));
        }
    }
}

// ================= fallback path (round-4, proven) for small ws =================
#define XS_ROW 72
__global__ __launch_bounds__(256, 4) void conv_mfma_fallback(
    const float* __restrict__ x, const u16* __restrict__ w3, float* __restrict__ out) {

    __shared__ __align__(16) u16 xs[6 * 33 * XS_ROW];

    const int tid = threadIdx.x;
    const int bid = blockIdx.x;
    const int hy0 = (bid & 15) << 1;
    const int dz  = (bid >> 4) & 31;
    const int b   = bid >> 9;

    const float* xb = x + (size_t)b * 64 * 35937;
    for (int i = tid; i < 1584; i += 256) {
        int w   = i % 33;
        int t   = i / 33;
        int q   = t & 7;
        int kh3 = t >> 3;
        int kd  = kh3 >= 3 ? 1 : 0;
        int kh  = kh3 - kd * 3;
        const float* p = xb + (size_t)(q << 3) * 35937 + (dz + kd) * 1089 + (hy0 + kh) * 33 + w;
        u32x4 v;
        v[0] = cvt_pk_bf16(p[0], p[35937]);
        v[1] = cvt_pk_bf16(p[2 * 35937], p[3 * 35937]);
        v[2] = cvt_pk_bf16(p[4 * 35937], p[5 * 35937]);
        v[3] = cvt_pk_bf16(p[6 * 35937], p[7 * 35937]);
        *reinterpret_cast<u32x4*>(&xs[(kh3 * 33 + w) * XS_ROW + (q << 3)]) = v;
    }
    __syncthreads();

    const int lane = tid & 63;
    const int ln   = lane & 15;
    const int g    = lane >> 4;
    const int n0w  = (tid >> 6) << 5;

    f32x4 acc[2][4];
#pragma unroll
    for (int nf = 0; nf < 2; ++nf)
#pragma unroll
        for (int mf = 0; mf < 4; ++mf)
            acc[nf][mf] = (f32x4){0.f, 0.f, 0.f, 0.f};

#pragma unroll
    for (int cb = 0; cb < 2; ++cb) {
        const int cbase = (cb << 5) + (g << 3);
#pragma unroll
        for (int kd = 0; kd < 2; ++kd) {
            bf16x8 wf[2][4];
#pragma unroll
            for (int nf = 0; nf < 2; ++nf)
#pragma unroll
                for (int kk = 0; kk < 4; ++kk) {
                    const int koff = (kd << 2) + kk;
                    const u16* p = w3 + (size_t)((((koff << 1) + cb) << 7)
                                   + n0w + (nf << 4) + ln) * 32 + (g << 3);
                    wf[nf][kk] = __builtin_bit_cast(bf16x8, *reinterpret_cast<const u16x8*>(p));
                }
#pragma unroll
            for (int kw = 0; kw < 2; ++kw) {
                bf16x8 xf[3][2];
#pragma unroll
                for (int hh = 0; hh < 3; ++hh)
#pragma unroll
                    for (int wh = 0; wh < 2; ++wh) {
                        const int rw = (kd * 3 + hh) * 33 + (wh << 4) + ln + kw;
                        xf[hh][wh] = __builtin_bit_cast(bf16x8,
                            *reinterpret_cast<const u16x8*>(&xs[rw * XS_ROW + cbase]));
                    }
#pragma unroll
                for (int kh = 0; kh < 2; ++kh)
#pragma unroll
                    for (int nf = 0; nf < 2; ++nf)
#pragma unroll
                        for (int mf = 0; mf < 4; ++mf)
                            acc[nf][mf] = __builtin_amdgcn_mfma_f32_16x16x32_bf16(
                                wf[nf][(kh << 1) + kw], xf[(mf >> 1) + kh][mf & 1],
                                acc[nf][mf], 0, 0, 0);
            }
        }
    }

    float* ob = out + ((size_t)b * 128) * 32768 + (dz << 10) + (hy0 << 5);
#pragma unroll
    for (int nf = 0; nf < 2; ++nf)
#pragma unroll
        for (int mf = 0; mf < 4; ++mf) {
            const int wx   = ((mf & 1) << 4) + ln;
            const int hrow = mf >> 1;
            float* o2 = ob + (hrow << 5) + wx;
#pragma unroll
            for (int r = 0; r < 4; ++r) {
                const int n = n0w + (nf << 4) + (g << 2) + r;
                float v = acc[nf][mf][r] + 1.0f;
                o2[(size_t)n << 15] = v * v;
            }
        }
}

extern "C" void kernel_launch(void* const* d_in, const int* in_sizes, int n_in,
                              void* d_out, int out_size, void* d_ws, size_t ws_size,
                              hipStream_t stream) {
    const float* x = (const float*)d_in[0];
    const float* w = (const float*)d_in[1];
    float* out = (float*)d_out;

    // ws layout: [w repack: 128KB][xT: 4356*4096 B][x32: 4356*128 B]
    const size_t W_BYTES   = 131072;
    const size_t XT_BYTES  = (size_t)4356 * 4096;
    const size_t X32_BYTES = (size_t)4356 * 128;
    const size_t NEED = W_BYTES + XT_BYTES + X32_BYTES;

    if (ws_size >= NEED) {
        u16* w4  = (u16*)d_ws;
        u16* xT  = (u16*)((char*)d_ws + W_BYTES);
        u16* x32 = (u16*)((char*)d_ws + W_BYTES + XT_BYTES);
        prepass_kernel<<<4612, 256, 0, stream>>>(x, w, xT, x32, w4);
        conv_mfma_kernel<<<1024, 256, 0, stream>>>(xT, x32, w4, out);
    } else {
        u16* w3 = (u16*)d_ws;
        repack_w_kernel<<<256, 256, 0, stream>>>(w, w3);
        conv_mfma_fallback<<<2048, 256, 0, stream>>>(x, w3, out);
    }
}